// Round 1
// 8192.783 us; speedup vs baseline: 1.0369x; 1.0369x over previous
//
#include <hip/hip_runtime.h>

typedef unsigned int u32;
typedef unsigned short u16;
typedef float f32x4 __attribute__((ext_vector_type(4)));
typedef short bf16x8 __attribute__((ext_vector_type(8)));
typedef u16 u16x4 __attribute__((ext_vector_type(4)));

#define N_NODES 100000
#define N_EDGES 3200000
#define MPAD 100096   // 782 * 128

__device__ __forceinline__ float bf2f(u16 b) { return __uint_as_float(((u32)b) << 16); }
__device__ __forceinline__ u16 f2bf(float f) {
  u32 u = __float_as_uint(f);
  u += 0x7fffu + ((u >> 16) & 1u);   // RNE
  return (u16)(u >> 16);
}

// ---------------- setup kernels ----------------

__global__ void count_kernel(const int* __restrict__ src, const int* __restrict__ dst,
                             int* deg, int* indeg) {
  int i = blockIdx.x * blockDim.x + threadIdx.x;
  if (i < N_EDGES) {
    atomicAdd(&deg[src[i]], 1);
    atomicAdd(&indeg[dst[i]], 1);
  }
}

__global__ void dis_kernel(const int* __restrict__ deg, float* __restrict__ dis) {
  int v = blockIdx.x * blockDim.x + threadIdx.x;
  if (v < N_NODES) dis[v] = deg[v] > 0 ? 1.0f / sqrtf((float)deg[v]) : 0.f;
}

// single-block exclusive scan, n = N_NODES
__global__ void scan_kernel(const int* __restrict__ in, int* __restrict__ rp,
                            int* __restrict__ cur, int n) {
  __shared__ int wtot[16];
  __shared__ int woff[16];
  const int tid = threadIdx.x;
  const int lane = tid & 63, wid = tid >> 6;
  int carry = 0;
  for (int base = 0; base < n; base += 1024) {
    int i = base + tid;
    int v = (i < n) ? in[i] : 0;
    int s = v;
#pragma unroll
    for (int off = 1; off < 64; off <<= 1) {
      int t = __shfl_up(s, off, 64);
      if (lane >= off) s += t;
    }
    if (lane == 63) wtot[wid] = s;
    __syncthreads();
    if (wid == 0) {
      int t = (lane < 16) ? wtot[lane] : 0;
#pragma unroll
      for (int off = 1; off < 16; off <<= 1) {
        int u = __shfl_up(t, off, 64);
        if (lane >= off) t += u;
      }
      if (lane < 16) woff[lane] = t;
    }
    __syncthreads();
    int wexcl = (wid == 0) ? 0 : woff[wid - 1];
    int excl = carry + wexcl + (s - v);
    if (i < n) { rp[i] = excl; cur[i] = excl; }
    carry += woff[15];
    __syncthreads();
  }
  if (tid == 0) rp[n] = carry;
}

__global__ void scatter_kernel(const int* __restrict__ src, const int* __restrict__ dst,
                               const float* __restrict__ dis, int* cursor,
                               int* __restrict__ ssrc, float* __restrict__ sw) {
  int i = blockIdx.x * blockDim.x + threadIdx.x;
  if (i >= N_EDGES) return;
  int s = src[i], d = dst[i];
  int pos = atomicAdd(&cursor[d], 1);
  ssrc[pos] = s;
  sw[pos] = -dis[s] * dis[d];
}

// W (3 x fi x fo fp32) -> WTh/WTl (NP x KP bf16 hi/lo), WT[n*KP + t*PW + r] = W[(t*fi+r)*fo + n]
__global__ void wt_kernel(const float* __restrict__ W, u16* __restrict__ WTh,
                          u16* __restrict__ WTl, int fi, int fo, int PW, int KP) {
  int idx = blockIdx.x * blockDim.x + threadIdx.x;
  if (idx >= 3 * fi * fo) return;
  int k = idx / fo, n = idx - k * fo;
  int t = k / fi, r = k - t * fi;
  float w = W[idx];
  u16 hb = f2bf(w);
  u16 lb = f2bf(w - bf2f(hb));
  WTh[(size_t)n * KP + t * PW + r] = hb;
  WTl[(size_t)n * KP + t * PW + r] = lb;
}

// ---------------- propagation (fp32): out[v] = dosub ? 2*acc - t0[v] : acc
// acc = sum_{e in CSR[v]} w[e] * in[src[e]]; one wave per node
template <int NC2, int F2>   // F2 = fi/2 float2 count; NC2 = ceil(F2/64)
__global__ __launch_bounds__(256) void prop_kernel(
    const int* __restrict__ rp, const int* __restrict__ ssrc, const float* __restrict__ sw,
    const float* __restrict__ in, const float* __restrict__ t0p, float* __restrict__ outp,
    int PW, int dosub) {
  int v = blockIdx.x * 4 + (threadIdx.x >> 6);
  if (v >= N_NODES) return;
  int lane = threadIdx.x & 63;
  float ax[NC2], ay[NC2];
#pragma unroll
  for (int c = 0; c < NC2; ++c) { ax[c] = 0.f; ay[c] = 0.f; }
  int e1 = rp[v + 1];
  for (int j = rp[v]; j < e1; ++j) {
    int s = ssrc[j];
    float wv = sw[j];
    const float2* row = reinterpret_cast<const float2*>(in + (size_t)s * PW);
#pragma unroll
    for (int c = 0; c < NC2; ++c) {
      int idx = c * 64 + lane;
      if (NC2 * 64 == F2 || idx < F2) {
        float2 p = row[idx];
        ax[c] += wv * p.x;
        ay[c] += wv * p.y;
      }
    }
  }
  float2* orow = reinterpret_cast<float2*>(outp + (size_t)v * PW);
  const float2* srow = reinterpret_cast<const float2*>(t0p + (size_t)v * PW);
#pragma unroll
  for (int c = 0; c < NC2; ++c) {
    int idx = c * 64 + lane;
    if (NC2 * 64 == F2 || idx < F2) {
      float xv = ax[c], yv = ay[c];
      if (dosub) {
        float2 q = srow[idx];
        xv = 2.f * xv - q.x;
        yv = 2.f * yv - q.y;
      }
      orow[idx] = make_float2(xv, yv);
    }
  }
}

// ---------------- GEMM: C = relu(A @ WT^T + b), fp32 in/out, bf16 hi/lo split MFMA
// block tile 128x128, 4 waves (2x2 of 64x64), BK=64; 3 products: Ah*Bh + Al*Bh + Ah*Bl
// LDS tiles are XOR-swizzled: element (row, col) lives at row*64 + (col ^ ((row&7)<<3)).
// Without the swizzle, fragment reads are a 16-way bank conflict (row stride = 128 B
// = one bank period; 16 lanes of a quad-group hit the same 16B column slot).
__global__ __launch_bounds__(256) void gemm_kernel(
    const float* __restrict__ A0, const float* __restrict__ A1, const float* __restrict__ A2,
    int PW, int PWSH, const u16* __restrict__ BTh, const u16* __restrict__ BTl, int KP,
    const float* __restrict__ bias, float* __restrict__ C,
    int ostride, int fo, int mlimit) {
  __shared__ u16 Ah[128 * 64];
  __shared__ u16 Al[128 * 64];
  __shared__ u16 Bt[128 * 64];
  const int tid = threadIdx.x;
  const int lane = tid & 63;
  const int wave = tid >> 6;
  const int m0 = blockIdx.x * 128;
  const int n0 = blockIdx.y * 128;
  const int wm = (wave & 1) * 64;
  const int wn = (wave >> 1) * 64;
  f32x4 acc[4][4] = {};

  const int arow = tid >> 4;        // 0..15
  const int acol = (tid & 15) * 4;  // fp32 quad col, 0..60
  // read-side swizzle: row&7 == lane&7 for every fragment row (wm, i*16 multiples of 8)
  const int lsw = (lane & 7) << 3;

  for (int k0 = 0; k0 < KP; k0 += 64) {
    int pi = k0 >> PWSH;
    const float* P = (pi == 0) ? A0 : (pi == 1 ? A1 : A2);
    int kc = k0 & (PW - 1);
    __syncthreads();
    // stage A hi/lo (swizzled store)
#pragma unroll
    for (int r8 = 0; r8 < 8; ++r8) {
      int row = arow + r8 * 16;
      float4 v4 = *reinterpret_cast<const float4*>(P + (size_t)(m0 + row) * PW + kc + acol);
      u16x4 h, l;
      float f[4] = {v4.x, v4.y, v4.z, v4.w};
#pragma unroll
      for (int q = 0; q < 4; ++q) {
        u16 hb = f2bf(f[q]);
        h[q] = hb;
        l[q] = f2bf(f[q] - bf2f(hb));
      }
      int sc = acol ^ ((row & 7) << 3);
      *reinterpret_cast<u16x4*>(&Ah[row * 64 + sc]) = h;
      *reinterpret_cast<u16x4*>(&Al[row * 64 + sc]) = l;
    }
    // stage B hi (swizzled store)
#pragma unroll
    for (int c = 0; c < 4; ++c) {
      int idx = c * 256 + tid;
      int row = idx >> 3, col8 = (idx & 7) * 8;
      uint4 vb = *reinterpret_cast<const uint4*>(BTh + (size_t)(n0 + row) * KP + k0 + col8);
      int sc = col8 ^ ((row & 7) << 3);
      *reinterpret_cast<uint4*>(&Bt[row * 64 + sc]) = vb;
    }
    __syncthreads();
    // passes 1-2: Ah*Bh, Al*Bh
#pragma unroll
    for (int hlf = 0; hlf < 2; ++hlf) {
      const u16* As = hlf ? Al : Ah;
#pragma unroll
      for (int ks = 0; ks < 64; ks += 32) {
        bf16x8 af[4], bfr[4];
        int ko = ks + (lane >> 4) * 8;
        int sko = ko ^ lsw;
#pragma unroll
        for (int i = 0; i < 4; ++i)
          af[i] = *reinterpret_cast<const bf16x8*>(&As[(wm + i * 16 + (lane & 15)) * 64 + sko]);
#pragma unroll
        for (int jj = 0; jj < 4; ++jj)
          bfr[jj] = *reinterpret_cast<const bf16x8*>(&Bt[(wn + jj * 16 + (lane & 15)) * 64 + sko]);
#pragma unroll
        for (int i = 0; i < 4; ++i)
#pragma unroll
          for (int jj = 0; jj < 4; ++jj)
            acc[i][jj] = __builtin_amdgcn_mfma_f32_16x16x32_bf16(af[i], bfr[jj], acc[i][jj], 0, 0, 0);
      }
    }
    __syncthreads();
    // stage B lo (reuse Bt, swizzled store)
#pragma unroll
    for (int c = 0; c < 4; ++c) {
      int idx = c * 256 + tid;
      int row = idx >> 3, col8 = (idx & 7) * 8;
      uint4 vb = *reinterpret_cast<const uint4*>(BTl + (size_t)(n0 + row) * KP + k0 + col8);
      int sc = col8 ^ ((row & 7) << 3);
      *reinterpret_cast<uint4*>(&Bt[row * 64 + sc]) = vb;
    }
    __syncthreads();
    // pass 3: Ah*Bl
#pragma unroll
    for (int ks = 0; ks < 64; ks += 32) {
      bf16x8 af[4], bfr[4];
      int ko = ks + (lane >> 4) * 8;
      int sko = ko ^ lsw;
#pragma unroll
      for (int i = 0; i < 4; ++i)
        af[i] = *reinterpret_cast<const bf16x8*>(&Ah[(wm + i * 16 + (lane & 15)) * 64 + sko]);
#pragma unroll
      for (int jj = 0; jj < 4; ++jj)
        bfr[jj] = *reinterpret_cast<const bf16x8*>(&Bt[(wn + jj * 16 + (lane & 15)) * 64 + sko]);
#pragma unroll
      for (int i = 0; i < 4; ++i)
#pragma unroll
        for (int jj = 0; jj < 4; ++jj)
          acc[i][jj] = __builtin_amdgcn_mfma_f32_16x16x32_bf16(af[i], bfr[jj], acc[i][jj], 0, 0, 0);
    }
  }

  const int qr = lane >> 4, lc = lane & 15;
#pragma unroll
  for (int jj = 0; jj < 4; ++jj) {
    int col = n0 + wn + jj * 16 + lc;
    if (col >= fo) continue;
    float bv = bias[col];
#pragma unroll
    for (int i = 0; i < 4; ++i) {
      int rowb = m0 + wm + i * 16 + qr * 4;
#pragma unroll
      for (int r = 0; r < 4; ++r) {
        int row = rowb + r;
        if (row < mlimit) {
          float vv = acc[i][jj][r] + bv;
          vv = vv > 0.f ? vv : 0.f;
          C[(size_t)row * ostride + col] = vv;
        }
      }
    }
  }
}

// ---------------- launch ----------------
extern "C" void kernel_launch(void* const* d_in, const int* in_sizes, int n_in,
                              void* d_out, int out_size, void* d_ws, size_t ws_size,
                              hipStream_t stream) {
  const float* x = (const float*)d_in[0];
  const int* ei = (const int*)d_in[1];
  const int* src = ei;
  const int* dst = ei + N_EDGES;
  const float* W1 = (const float*)d_in[2];
  const float* b1 = (const float*)d_in[3];
  const float* W2 = (const float*)d_in[4];
  const float* b2 = (const float*)d_in[5];
  const float* W3 = (const float*)d_in[6];
  const float* b3 = (const float*)d_in[7];
  float* out = (float*)d_out;

  char* ws = (char*)d_ws;
  size_t o = 0;
  auto alloc = [&](size_t bytes) { size_t r = o; o += (bytes + 255) & ~(size_t)255; return r; };
  int* deg = (int*)(ws + alloc((size_t)N_NODES * 4));
  int* indeg = (int*)(ws + alloc((size_t)N_NODES * 4));
  int* rp = (int*)(ws + alloc((size_t)(N_NODES + 1) * 4));
  int* cur = (int*)(ws + alloc((size_t)N_NODES * 4));
  float* dis = (float*)(ws + alloc((size_t)N_NODES * 4));
  int* ssrc = (int*)(ws + alloc((size_t)N_EDGES * 4));
  float* sw = (float*)(ws + alloc((size_t)N_EDGES * 4));
  u16* WT1h = (u16*)(ws + alloc((size_t)256 * 384 * 2));
  u16* WT1l = (u16*)(ws + alloc((size_t)256 * 384 * 2));
  u16* WT2h = (u16*)(ws + alloc((size_t)512 * 768 * 2));
  u16* WT2l = (u16*)(ws + alloc((size_t)512 * 768 * 2));
  u16* WT3h = (u16*)(ws + alloc((size_t)1024 * 1536 * 2));
  u16* WT3l = (u16*)(ws + alloc((size_t)1024 * 1536 * 2));
  // three 205-MB regions, lifetime-aliased fp32 planes (MPAD rows each)
  const size_t SZ1 = (size_t)MPAD * 128 * 4;   // 51.25 MB
  const size_t SZ2 = (size_t)MPAD * 256 * 4;   // 102.5 MB
  const size_t SZ3 = (size_t)MPAD * 512 * 4;   // 205.0 MB
  char* regA = ws + alloc(SZ3);
  char* regB = ws + alloc(SZ3);
  char* regC = ws + alloc(SZ3);
  float* P30 = (float*)regA;
  float* P20 = (float*)regB;            // dies after gemm2
  float* P21 = (float*)(regB + SZ2);    // dies after gemm2
  float* P31 = (float*)regB;            // born prop3a (after gemm2)
  float* P10 = (float*)regC;                  // dies after gemm1
  float* P11 = (float*)(regC + SZ1);          // dies after gemm1
  float* P12 = (float*)(regC + 2 * SZ1);      // dies after gemm1
  float* P22 = (float*)regC;            // born prop2b (after gemm1), dies after gemm2
  float* P32 = (float*)regC;            // born prop3b (after gemm2)
  // total ws use ~655 MB

  hipMemsetAsync(deg, 0, (size_t)N_NODES * 4, stream);
  hipMemsetAsync(indeg, 0, (size_t)N_NODES * 4, stream);
  hipMemsetAsync(WT1h, 0, (size_t)256 * 384 * 2 * 2, stream);   // h+l contiguous
  hipMemsetAsync(WT2h, 0, (size_t)512 * 768 * 2 * 2, stream);
  hipMemsetAsync(WT3h, 0, (size_t)1024 * 1536 * 2 * 2, stream);

  count_kernel<<<(N_EDGES + 255) / 256, 256, 0, stream>>>(src, dst, deg, indeg);
  dis_kernel<<<(N_NODES + 255) / 256, 256, 0, stream>>>(deg, dis);
  scan_kernel<<<1, 1024, 0, stream>>>(indeg, rp, cur, N_NODES);
  scatter_kernel<<<(N_EDGES + 255) / 256, 256, 0, stream>>>(src, dst, dis, cur, ssrc, sw);
  wt_kernel<<<(3 * 128 * 250 + 255) / 256, 256, 0, stream>>>(W1, WT1h, WT1l, 128, 250, 128, 384);
  wt_kernel<<<(3 * 250 * 500 + 255) / 256, 256, 0, stream>>>(W2, WT2h, WT2l, 250, 500, 256, 768);
  wt_kernel<<<(3 * 500 * 1000 + 255) / 256, 256, 0, stream>>>(W3, WT3h, WT3l, 500, 1000, 512, 1536);
  hipMemcpyAsync(P10, x, (size_t)N_NODES * 128 * 4, hipMemcpyDeviceToDevice, stream);

  dim3 pgrid((N_NODES + 3) / 4);
  // layer 1 (fi=128, PW=128, fo=250)
  prop_kernel<1, 64><<<pgrid, 256, 0, stream>>>(rp, ssrc, sw, P10, P10, P11, 128, 0);
  prop_kernel<1, 64><<<pgrid, 256, 0, stream>>>(rp, ssrc, sw, P11, P10, P12, 128, 1);
  gemm_kernel<<<dim3(MPAD / 128, 2), 256, 0, stream>>>(P10, P11, P12, 128, 7, WT1h, WT1l, 384, b1, P20, 256, 250, MPAD);
  // layer 2 (fi=250, PW=256, fo=500)
  prop_kernel<2, 125><<<pgrid, 256, 0, stream>>>(rp, ssrc, sw, P20, P20, P21, 256, 0);
  prop_kernel<2, 125><<<pgrid, 256, 0, stream>>>(rp, ssrc, sw, P21, P20, P22, 256, 1);
  gemm_kernel<<<dim3(MPAD / 128, 4), 256, 0, stream>>>(P20, P21, P22, 256, 8, WT2h, WT2l, 768, b2, P30, 512, 500, MPAD);
  // layer 3 (fi=500, PW=512, fo=1000)
  prop_kernel<4, 250><<<pgrid, 256, 0, stream>>>(rp, ssrc, sw, P30, P30, P31, 512, 0);
  prop_kernel<4, 250><<<pgrid, 256, 0, stream>>>(rp, ssrc, sw, P31, P30, P32, 512, 1);
  gemm_kernel<<<dim3(MPAD / 128, 8), 256, 0, stream>>>(P30, P31, P32, 512, 9, WT3h, WT3l, 1536, b3, out, 1000, 1000, N_NODES);

  (void)in_sizes; (void)n_in; (void)out_size; (void)ws_size;
}